// Round 6
// baseline (410.082 us; speedup 1.0000x reference)
//
#include <hip/hip_runtime.h>

#define NN 8192
#define DD 256
#define RCAP 512   // per-row CSR capacity in workspace

typedef float v4f __attribute__((ext_vector_type(4)));
typedef unsigned short u16x4 __attribute__((ext_vector_type(4)));

__device__ __forceinline__ unsigned short f2bf_rne(float x) {
    unsigned u = __float_as_uint(x);
    u += 0x7fffu + ((u >> 16) & 1u);
    return (unsigned short)(u >> 16);
}

__device__ __forceinline__ float4 bf4_to_f4(u16x4 u) {
    float4 r;
    r.x = __uint_as_float((unsigned)u.x << 16);
    r.y = __uint_as_float((unsigned)u.y << 16);
    r.z = __uint_as_float((unsigned)u.z << 16);
    r.w = __uint_as_float((unsigned)u.w << 16);
    return r;
}

// Fused prep: scores[row] = inputs[row,:].Hv AND (optionally) bf16 copy of inputs.
template <bool WRITE_IB>
__global__ __launch_bounds__(256) void prep_kernel(const float* __restrict__ inputs,
                                                   const float* __restrict__ Hv,
                                                   float* __restrict__ scores,
                                                   unsigned short* __restrict__ ib) {
    int wave = threadIdx.x >> 6;
    int lane = threadIdx.x & 63;
    int row  = blockIdx.x * 4 + wave;
    float4 v = ((const float4*)(inputs + (size_t)row * DD))[lane];
    if (WRITE_IB) {
        u16x4 u;
        u.x = f2bf_rne(v.x); u.y = f2bf_rne(v.y); u.z = f2bf_rne(v.z); u.w = f2bf_rne(v.w);
        ((u16x4*)(ib + (size_t)row * DD))[lane] = u;
    }
    float4 h = ((const float4*)Hv)[lane];
    float s = v.x * h.x + v.y * h.y + v.z * h.z + v.w * h.w;
    #pragma unroll
    for (int off = 32; off > 0; off >>= 1) s += __shfl_down(s, off, 64);
    if (lane == 0) scores[row] = s;
}

// Phase 1: stream adj, build per-row CSR of (j, e=exp(a*score[j])) in workspace.
// Pure stream + short tail: the exp/scores-load step is ONE coalesced parallel
// pass over the compacted list (not 32 divergent branches with dependent loads).
__global__ __launch_bounds__(256) void build_kernel(const float* __restrict__ adj,
                                                    const float* __restrict__ scores,
                                                    float2* __restrict__ csr,
                                                    int* __restrict__ cnt) {
    __shared__ float2 s_ja[RCAP];
    __shared__ int s_wsum[4];

    const int row  = blockIdx.x;
    const int tid  = threadIdx.x;
    const int lane = tid & 63;
    const int wave = tid >> 6;

    const v4f* arow4 = (const v4f*)(adj + (size_t)row * NN);
    v4f a[8];
#pragma unroll
    for (int c = 0; c < 8; ++c) a[c] = arow4[c * 256 + tid];

    int nz = 0;
#pragma unroll
    for (int c = 0; c < 8; ++c)
        nz += (a[c].x != 0.f) + (a[c].y != 0.f) + (a[c].z != 0.f) + (a[c].w != 0.f);

    int pre = nz;
#pragma unroll
    for (int off = 1; off < 64; off <<= 1) {
        int t = __shfl_up(pre, off, 64);
        if (lane >= off) pre += t;
    }
    if (lane == 63) s_wsum[wave] = pre;
    __syncthreads();
    int base = 0, total = 0;
#pragma unroll
    for (int w = 0; w < 4; ++w) {
        int t = s_wsum[w];
        if (w < wave) base += t;
        total += t;
    }

    // Pass 1: write (j, a) pairs to LDS — stores only, no dependent loads.
    int off = base + pre - nz;
#pragma unroll
    for (int c = 0; c < 8; ++c) {
        int j0 = c * 1024 + tid * 4;
        float v;
        v = a[c].x; if (v != 0.f) { if (off < RCAP) s_ja[off] = make_float2(__int_as_float(j0 + 0), v); off++; }
        v = a[c].y; if (v != 0.f) { if (off < RCAP) s_ja[off] = make_float2(__int_as_float(j0 + 1), v); off++; }
        v = a[c].z; if (v != 0.f) { if (off < RCAP) s_ja[off] = make_float2(__int_as_float(j0 + 2), v); off++; }
        v = a[c].w; if (v != 0.f) { if (off < RCAP) s_ja[off] = make_float2(__int_as_float(j0 + 3), v); off++; }
    }
    __syncthreads();

    // Pass 2: one coalesced parallel step: load scores[j], exp, write CSR.
    int lim = total <= RCAP ? total : RCAP;
    for (int k = tid; k < lim; k += 256) {
        float2 ja = s_ja[k];
        int j = __float_as_int(ja.x);
        float e = __expf(ja.y * scores[j]);
        csr[(size_t)row * RCAP + k] = make_float2(ja.x, e);
    }
    if (tid == 0) cnt[row] = total;
}

// Readlane gather over an entry list (global CSR or LDS): wave owns [kbeg,kend).
__device__ __forceinline__ void gather_range(const float2* __restrict__ entries,
                                             int kbeg, int kend,
                                             const unsigned short* __restrict__ ib,
                                             int lane, int lane4,
                                             float4& acc, float& ssum) {
    for (int b = kbeg; b < kend; b += 64) {
        int nb = kend - b; nb = nb > 64 ? 64 : nb;
        float2 je = entries[b + (lane < nb ? lane : 0)];
        int jl = __float_as_int(je.x);
        int el = __float_as_int(je.y);
        int m = 0;
        for (; m + 8 <= nb; m += 8) {
            int js[8]; float es[8]; float4 f[8];
            #pragma unroll
            for (int u = 0; u < 8; ++u) {
                js[u] = __builtin_amdgcn_readlane(jl, m + u);
                es[u] = __uint_as_float(__builtin_amdgcn_readlane(el, m + u));
            }
            #pragma unroll
            for (int u = 0; u < 8; ++u)
                f[u] = bf4_to_f4(*(const u16x4*)(ib + (size_t)js[u] * DD + lane4));
            #pragma unroll
            for (int u = 0; u < 8; ++u) {
                acc.x += es[u] * f[u].x; acc.y += es[u] * f[u].y;
                acc.z += es[u] * f[u].z; acc.w += es[u] * f[u].w;
                ssum  += es[u];
            }
        }
        for (; m < nb; ++m) {
            int   j = __builtin_amdgcn_readlane(jl, m);
            float e = __uint_as_float(__builtin_amdgcn_readlane(el, m));
            float4 f = bf4_to_f4(*(const u16x4*)(ib + (size_t)j * DD + lane4));
            acc.x += e * f.x; acc.y += e * f.y; acc.z += e * f.z; acc.w += e * f.w;
            ssum += e;
        }
    }
}

// Phase 2: gather. No competing adj stream -> 4 MB bf16 table stays L2-resident.
__global__ __launch_bounds__(256) void gather_kernel(const float2* __restrict__ csr,
                                                     const int* __restrict__ cnt,
                                                     const unsigned short* __restrict__ ib,
                                                     const float* __restrict__ adj,
                                                     const float* __restrict__ scores,
                                                     float* __restrict__ out) {
    __shared__ float  s_red[4 * DD];
    __shared__ float  s_ssum[4];
    __shared__ float2 s_je[1024];
    __shared__ int    s_cnt;

    const int row   = blockIdx.x;
    const int tid   = threadIdx.x;
    const int lane  = tid & 63;
    const int wave  = tid >> 6;
    const int lane4 = lane * 4;

    int total = cnt[row];
    float4 acc = make_float4(0.f, 0.f, 0.f, 0.f);
    float ssum = 0.f;

    if (total <= RCAP) {
        const float2* rowp = csr + (size_t)row * RCAP;
        gather_range(rowp, wave * total / 4, (wave + 1) * total / 4,
                     ib, lane, lane4, acc, ssum);
    } else {
        // Slow path (any-density correctness): chunked re-scan of the adj row.
        const float* arow = adj + (size_t)row * NN;
        for (int c = 0; c < 8; ++c) {
            if (tid == 0) s_cnt = 0;
            __syncthreads();
            float4 a = ((const float4*)(arow + c * 1024))[tid];
            int j0 = c * 1024 + tid * 4;
            float v;
            v = a.x; if (v != 0.f) { int k = atomicAdd(&s_cnt, 1); s_je[k] = make_float2(__int_as_float(j0 + 0), __expf(v * scores[j0 + 0])); }
            v = a.y; if (v != 0.f) { int k = atomicAdd(&s_cnt, 1); s_je[k] = make_float2(__int_as_float(j0 + 1), __expf(v * scores[j0 + 1])); }
            v = a.z; if (v != 0.f) { int k = atomicAdd(&s_cnt, 1); s_je[k] = make_float2(__int_as_float(j0 + 2), __expf(v * scores[j0 + 2])); }
            v = a.w; if (v != 0.f) { int k = atomicAdd(&s_cnt, 1); s_je[k] = make_float2(__int_as_float(j0 + 3), __expf(v * scores[j0 + 3])); }
            __syncthreads();
            int tc = s_cnt;
            gather_range(s_je, wave * tc / 4, (wave + 1) * tc / 4,
                         ib, lane, lane4, acc, ssum);
            __syncthreads();
        }
    }

    if (lane == 0) s_ssum[wave] = ssum;
    *(float4*)&s_red[wave * DD + lane4] = acc;
    __syncthreads();
    float tot = s_ssum[0] + s_ssum[1] + s_ssum[2] + s_ssum[3];
    float r = s_red[0 * DD + tid] + s_red[1 * DD + tid] + s_red[2 * DD + tid] + s_red[3 * DD + tid];
    out[(size_t)row * DD + tid] = (tot > 0.f) ? r / tot : 0.f;
}

// Compact fallback if ws is too small for the CSR layout (not expected):
// monolithic chunked kernel, fp32 gather.
__global__ __launch_bounds__(256) void attn_fallback(const float* __restrict__ adj,
                                                     const float* __restrict__ inputs,
                                                     const float* __restrict__ scores,
                                                     float* __restrict__ out) {
    __shared__ int   s_j[1024];
    __shared__ float s_e[1024];
    __shared__ int   s_cnt;
    const int row = blockIdx.x;
    const int tid = threadIdx.x;
    const float* arow = adj + (size_t)row * NN;
    float acc = 0.f, ssum = 0.f;
    for (int base = 0; base < NN; base += 1024) {
        if (tid == 0) s_cnt = 0;
        __syncthreads();
        float4 a = ((const float4*)(arow + base))[tid];
        int j0 = base + tid * 4;
        if (a.x != 0.f) { int k = atomicAdd(&s_cnt, 1); s_j[k] = j0 + 0; s_e[k] = __expf(a.x * scores[j0 + 0]); }
        if (a.y != 0.f) { int k = atomicAdd(&s_cnt, 1); s_j[k] = j0 + 1; s_e[k] = __expf(a.y * scores[j0 + 1]); }
        if (a.z != 0.f) { int k = atomicAdd(&s_cnt, 1); s_j[k] = j0 + 2; s_e[k] = __expf(a.z * scores[j0 + 2]); }
        if (a.w != 0.f) { int k = atomicAdd(&s_cnt, 1); s_j[k] = j0 + 3; s_e[k] = __expf(a.w * scores[j0 + 3]); }
        __syncthreads();
        int c = s_cnt;
        for (int k = 0; k < c; ++k) {
            float e = s_e[k];
            acc  += e * inputs[(size_t)s_j[k] * DD + tid];
            ssum += e;
        }
        __syncthreads();
    }
    out[(size_t)row * DD + tid] = (ssum > 0.f) ? acc / ssum : 0.f;
}

extern "C" void kernel_launch(void* const* d_in, const int* in_sizes, int n_in,
                              void* d_out, int out_size, void* d_ws, size_t ws_size,
                              hipStream_t stream) {
    const float* inputs = (const float*)d_in[0];  // [N, D] fp32
    const float* adj    = (const float*)d_in[1];  // [N, N] fp32
    const float* Hv     = (const float*)d_in[2];  // [D, 1] fp32
    float* out = (float*)d_out;                   // [N, D] fp32

    char* ws = (char*)d_ws;
    float*          scores = (float*)ws;                                   // 32 KB
    unsigned short* ib     = (unsigned short*)(ws + 32768);                // 4 MB
    int*            cnt    = (int*)(ws + 32768 + (size_t)NN * DD * 2);     // 32 KB
    float2*         csr    = (float2*)(ws + 65536 + (size_t)NN * DD * 2);  // 32 MB

    const size_t need = 65536 + (size_t)NN * DD * 2 + (size_t)NN * RCAP * sizeof(float2);

    if (ws_size >= need) {
        prep_kernel<true><<<NN / 4, 256, 0, stream>>>(inputs, Hv, scores, ib);
        build_kernel<<<NN, 256, 0, stream>>>(adj, scores, csr, cnt);
        gather_kernel<<<NN, 256, 0, stream>>>(csr, cnt, ib, adj, scores, out);
    } else {
        prep_kernel<false><<<NN / 4, 256, 0, stream>>>(inputs, Hv, scores, nullptr);
        attn_fallback<<<NN, 256, 0, stream>>>(adj, inputs, scores, out);
    }
}

// Round 7
// 397.431 us; speedup vs baseline: 1.0318x; 1.0318x over previous
//
#include <hip/hip_runtime.h>

#define NN 8192
#define DD 256
#define RCAP 512   // per-row CSR capacity in workspace

typedef float v4f __attribute__((ext_vector_type(4)));
typedef unsigned short u16x4 __attribute__((ext_vector_type(4)));

__device__ __forceinline__ unsigned short f2bf_rne(float x) {
    unsigned u = __float_as_uint(x);
    u += 0x7fffu + ((u >> 16) & 1u);
    return (unsigned short)(u >> 16);
}

__device__ __forceinline__ float4 bf4_to_f4(u16x4 u) {
    float4 r;
    r.x = __uint_as_float((unsigned)u.x << 16);
    r.y = __uint_as_float((unsigned)u.y << 16);
    r.z = __uint_as_float((unsigned)u.z << 16);
    r.w = __uint_as_float((unsigned)u.w << 16);
    return r;
}

// Fused prep: scores[row] = inputs[row,:].Hv AND (optionally) bf16 copy of inputs.
template <bool WRITE_IB>
__global__ __launch_bounds__(256) void prep_kernel(const float* __restrict__ inputs,
                                                   const float* __restrict__ Hv,
                                                   float* __restrict__ scores,
                                                   unsigned short* __restrict__ ib) {
    int wave = threadIdx.x >> 6;
    int lane = threadIdx.x & 63;
    int row  = blockIdx.x * 4 + wave;
    float4 v = ((const float4*)(inputs + (size_t)row * DD))[lane];
    if (WRITE_IB) {
        u16x4 u;
        u.x = f2bf_rne(v.x); u.y = f2bf_rne(v.y); u.z = f2bf_rne(v.z); u.w = f2bf_rne(v.w);
        ((u16x4*)(ib + (size_t)row * DD))[lane] = u;
    }
    float4 h = ((const float4*)Hv)[lane];
    float s = v.x * h.x + v.y * h.y + v.z * h.z + v.w * h.w;
    #pragma unroll
    for (int off = 32; off > 0; off >>= 1) s += __shfl_down(s, off, 64);
    if (lane == 0) scores[row] = s;
}

// ---------------- Phase 1: build CSR ----------------

__device__ __forceinline__ void process_row(const v4f a[8], int row, int tid, int lane, int wave,
                                            const float* __restrict__ scores,
                                            float2* __restrict__ csr, int* __restrict__ cnt,
                                            float2* s_ja, int* s_wsum) {
    int nz = 0;
#pragma unroll
    for (int c = 0; c < 8; ++c)
        nz += (a[c].x != 0.f) + (a[c].y != 0.f) + (a[c].z != 0.f) + (a[c].w != 0.f);

    int pre = nz;
#pragma unroll
    for (int off = 1; off < 64; off <<= 1) {
        int t = __shfl_up(pre, off, 64);
        if (lane >= off) pre += t;
    }
    if (lane == 63) s_wsum[wave] = pre;
    __syncthreads();
    int base = 0, total = 0;
#pragma unroll
    for (int w = 0; w < 4; ++w) {
        int t = s_wsum[w];
        if (w < wave) base += t;
        total += t;
    }

    // Pass 1: (j, a) pairs to LDS — stores only.
    int off = base + pre - nz;
#pragma unroll
    for (int c = 0; c < 8; ++c) {
        int j0 = c * 1024 + tid * 4;
        float v;
        v = a[c].x; if (v != 0.f) { if (off < RCAP) s_ja[off] = make_float2(__int_as_float(j0 + 0), v); off++; }
        v = a[c].y; if (v != 0.f) { if (off < RCAP) s_ja[off] = make_float2(__int_as_float(j0 + 1), v); off++; }
        v = a[c].z; if (v != 0.f) { if (off < RCAP) s_ja[off] = make_float2(__int_as_float(j0 + 2), v); off++; }
        v = a[c].w; if (v != 0.f) { if (off < RCAP) s_ja[off] = make_float2(__int_as_float(j0 + 3), v); off++; }
    }
    __syncthreads();

    // Pass 2: coalesced: load scores[j], exp, write CSR.
    int lim = total <= RCAP ? total : RCAP;
    for (int k = tid; k < lim; k += 256) {
        float2 ja = s_ja[k];
        int j = __float_as_int(ja.x);
        float e = __expf(ja.y * scores[j]);
        csr[(size_t)row * RCAP + k] = make_float2(ja.x, e);
    }
    if (tid == 0) cnt[row] = total;
    __syncthreads();   // protect s_ja / s_wsum reuse by the next row
}

// 2 rows per block; all 16 dwordx4 issued before any use -> row1's 8 loads stay
// in flight (vmcnt(8)) while row0 is scanned/compacted/written.
__global__ __launch_bounds__(256) void build_kernel(const float* __restrict__ adj,
                                                    const float* __restrict__ scores,
                                                    float2* __restrict__ csr,
                                                    int* __restrict__ cnt) {
    __shared__ float2 s_ja[RCAP];
    __shared__ int s_wsum[4];

    const int tid  = threadIdx.x;
    const int lane = tid & 63;
    const int wave = tid >> 6;
    const int row0 = blockIdx.x * 2;

    const v4f* p0 = (const v4f*)(adj + (size_t)row0 * NN);
    const v4f* p1 = (const v4f*)(adj + (size_t)(row0 + 1) * NN);
    v4f a0[8], a1[8];
#pragma unroll
    for (int c = 0; c < 8; ++c) a0[c] = __builtin_nontemporal_load(&p0[c * 256 + tid]);
#pragma unroll
    for (int c = 0; c < 8; ++c) a1[c] = __builtin_nontemporal_load(&p1[c * 256 + tid]);

    process_row(a0, row0,     tid, lane, wave, scores, csr, cnt, s_ja, s_wsum);
    process_row(a1, row0 + 1, tid, lane, wave, scores, csr, cnt, s_ja, s_wsum);
}

// ---------------- Phase 2: gather ----------------

__device__ __forceinline__ void batch8(const unsigned short* __restrict__ ib,
                                       int jl, int el, int m, int lane4,
                                       float4& acc, float& ssum) {
    int js[8]; float es[8]; float4 f[8];
#pragma unroll
    for (int u = 0; u < 8; ++u) {
        js[u] = __builtin_amdgcn_readlane(jl, m + u);
        es[u] = __uint_as_float(__builtin_amdgcn_readlane(el, m + u));
    }
#pragma unroll
    for (int u = 0; u < 8; ++u)
        f[u] = bf4_to_f4(*(const u16x4*)(ib + (size_t)js[u] * DD + lane4));
#pragma unroll
    for (int u = 0; u < 8; ++u) {
        acc.x += es[u] * f[u].x; acc.y += es[u] * f[u].y;
        acc.z += es[u] * f[u].z; acc.w += es[u] * f[u].w;
        ssum  += es[u];
    }
}

// Interleaved dual-range gather: two independent chains -> up to 16 loads in
// flight per wave. Lanes beyond a chunk's count get e=0 (padded, branch-free).
__device__ void gather_pair(const float2* __restrict__ eA, int bA, int keA,
                            const float2* __restrict__ eB, int bB, int keB,
                            const unsigned short* __restrict__ ib,
                            int lane, int lane4,
                            float4& accA, float& ssA, float4& accB, float& ssB) {
    while (bA < keA || bB < keB) {
        int nA = keA - bA; nA = nA > 64 ? 64 : nA;
        int nB = keB - bB; nB = nB > 64 ? 64 : nB;
        int jlA = 0, elA = 0, jlB = 0, elB = 0;
        if (nA > 0) {
            float2 je = eA[bA + (lane < nA ? lane : 0)];
            if (lane >= nA) je.y = 0.f;
            jlA = __float_as_int(je.x); elA = __float_as_int(je.y);
        }
        if (nB > 0) {
            float2 je = eB[bB + (lane < nB ? lane : 0)];
            if (lane >= nB) je.y = 0.f;
            jlB = __float_as_int(je.x); elB = __float_as_int(je.y);
        }
        int nA8 = nA > 0 ? ((nA + 7) & ~7) : 0;
        int nB8 = nB > 0 ? ((nB + 7) & ~7) : 0;
        int mx = nA8 > nB8 ? nA8 : nB8;
        for (int m = 0; m < mx; m += 8) {
            if (m < nA8) batch8(ib, jlA, elA, m, lane4, accA, ssA);
            if (m < nB8) batch8(ib, jlB, elB, m, lane4, accB, ssB);
        }
        if (nA > 0) bA += nA;
        if (nB > 0) bB += nB;
    }
}

// Slow path: chunked re-scan of one adj row (any density). Block-uniform entry.
__device__ void slow_row(const float* __restrict__ adj, int row,
                         const float* __restrict__ scores,
                         const unsigned short* __restrict__ ib,
                         float2* s_je, int* s_cnt,
                         int tid, int lane, int lane4, int wave,
                         float4& acc, float& ssum) {
    const float* arow = adj + (size_t)row * NN;
    for (int c = 0; c < 8; ++c) {
        if (tid == 0) *s_cnt = 0;
        __syncthreads();
        float4 a = ((const float4*)(arow + c * 1024))[tid];
        int j0 = c * 1024 + tid * 4;
        float v;
        v = a.x; if (v != 0.f) { int k = atomicAdd(s_cnt, 1); s_je[k] = make_float2(__int_as_float(j0 + 0), __expf(v * scores[j0 + 0])); }
        v = a.y; if (v != 0.f) { int k = atomicAdd(s_cnt, 1); s_je[k] = make_float2(__int_as_float(j0 + 1), __expf(v * scores[j0 + 1])); }
        v = a.z; if (v != 0.f) { int k = atomicAdd(s_cnt, 1); s_je[k] = make_float2(__int_as_float(j0 + 2), __expf(v * scores[j0 + 2])); }
        v = a.w; if (v != 0.f) { int k = atomicAdd(s_cnt, 1); s_je[k] = make_float2(__int_as_float(j0 + 3), __expf(v * scores[j0 + 3])); }
        __syncthreads();
        int tc = *s_cnt;
        float4 dummy = make_float4(0.f, 0.f, 0.f, 0.f); float sdummy = 0.f;
        gather_pair(s_je, wave * tc / 4, (wave + 1) * tc / 4,
                    s_je, 0, 0, ib, lane, lane4, acc, ssum, dummy, sdummy);
        __syncthreads();
    }
}

// 2 rows per block.
__global__ __launch_bounds__(256) void gather_kernel(const float2* __restrict__ csr,
                                                     const int* __restrict__ cnt,
                                                     const unsigned short* __restrict__ ib,
                                                     const float* __restrict__ adj,
                                                     const float* __restrict__ scores,
                                                     float* __restrict__ out) {
    __shared__ float  s_red[2][4 * DD];
    __shared__ float  s_ss[2][4];
    __shared__ float2 s_je[1024];
    __shared__ int    s_cnt;

    const int tid   = threadIdx.x;
    const int lane  = tid & 63;
    const int wave  = tid >> 6;
    const int lane4 = lane * 4;
    const int row0  = blockIdx.x * 2;
    const int row1  = row0 + 1;

    int t0 = cnt[row0];
    int t1 = cnt[row1];
    float4 acc0 = make_float4(0.f, 0.f, 0.f, 0.f), acc1 = acc0;
    float ss0 = 0.f, ss1 = 0.f;

    if (t0 <= RCAP && t1 <= RCAP) {
        gather_pair(csr + (size_t)row0 * RCAP, wave * t0 / 4, (wave + 1) * t0 / 4,
                    csr + (size_t)row1 * RCAP, wave * t1 / 4, (wave + 1) * t1 / 4,
                    ib, lane, lane4, acc0, ss0, acc1, ss1);
    } else {
        // Rare/any-density path; block-uniform branches.
        if (t0 <= RCAP) {
            float4 d = make_float4(0.f, 0.f, 0.f, 0.f); float sd = 0.f;
            gather_pair(csr + (size_t)row0 * RCAP, wave * t0 / 4, (wave + 1) * t0 / 4,
                        csr, 0, 0, ib, lane, lane4, acc0, ss0, d, sd);
        } else {
            slow_row(adj, row0, scores, ib, s_je, &s_cnt, tid, lane, lane4, wave, acc0, ss0);
        }
        if (t1 <= RCAP) {
            float4 d = make_float4(0.f, 0.f, 0.f, 0.f); float sd = 0.f;
            gather_pair(csr + (size_t)row1 * RCAP, wave * t1 / 4, (wave + 1) * t1 / 4,
                        csr, 0, 0, ib, lane, lane4, acc1, ss1, d, sd);
        } else {
            slow_row(adj, row1, scores, ib, s_je, &s_cnt, tid, lane, lane4, wave, acc1, ss1);
        }
    }

    if (lane == 0) { s_ss[0][wave] = ss0; s_ss[1][wave] = ss1; }
    *(float4*)&s_red[0][wave * DD + lane4] = acc0;
    *(float4*)&s_red[1][wave * DD + lane4] = acc1;
    __syncthreads();
    float tot0 = s_ss[0][0] + s_ss[0][1] + s_ss[0][2] + s_ss[0][3];
    float tot1 = s_ss[1][0] + s_ss[1][1] + s_ss[1][2] + s_ss[1][3];
    float r0 = s_red[0][0 * DD + tid] + s_red[0][1 * DD + tid] + s_red[0][2 * DD + tid] + s_red[0][3 * DD + tid];
    float r1 = s_red[1][0 * DD + tid] + s_red[1][1 * DD + tid] + s_red[1][2 * DD + tid] + s_red[1][3 * DD + tid];
    out[(size_t)row0 * DD + tid] = (tot0 > 0.f) ? r0 / tot0 : 0.f;
    out[(size_t)row1 * DD + tid] = (tot1 > 0.f) ? r1 / tot1 : 0.f;
}

// Compact fallback if ws is too small for the CSR layout (not expected).
__global__ __launch_bounds__(256) void attn_fallback(const float* __restrict__ adj,
                                                     const float* __restrict__ inputs,
                                                     const float* __restrict__ scores,
                                                     float* __restrict__ out) {
    __shared__ int   s_j[1024];
    __shared__ float s_e[1024];
    __shared__ int   s_cnt;
    const int row = blockIdx.x;
    const int tid = threadIdx.x;
    const float* arow = adj + (size_t)row * NN;
    float acc = 0.f, ssum = 0.f;
    for (int base = 0; base < NN; base += 1024) {
        if (tid == 0) s_cnt = 0;
        __syncthreads();
        float4 a = ((const float4*)(arow + base))[tid];
        int j0 = base + tid * 4;
        if (a.x != 0.f) { int k = atomicAdd(&s_cnt, 1); s_j[k] = j0 + 0; s_e[k] = __expf(a.x * scores[j0 + 0]); }
        if (a.y != 0.f) { int k = atomicAdd(&s_cnt, 1); s_j[k] = j0 + 1; s_e[k] = __expf(a.y * scores[j0 + 1]); }
        if (a.z != 0.f) { int k = atomicAdd(&s_cnt, 1); s_j[k] = j0 + 2; s_e[k] = __expf(a.z * scores[j0 + 2]); }
        if (a.w != 0.f) { int k = atomicAdd(&s_cnt, 1); s_j[k] = j0 + 3; s_e[k] = __expf(a.w * scores[j0 + 3]); }
        __syncthreads();
        int c = s_cnt;
        for (int k = 0; k < c; ++k) {
            float e = s_e[k];
            acc  += e * inputs[(size_t)s_j[k] * DD + tid];
            ssum += e;
        }
        __syncthreads();
    }
    out[(size_t)row * DD + tid] = (ssum > 0.f) ? acc / ssum : 0.f;
}

extern "C" void kernel_launch(void* const* d_in, const int* in_sizes, int n_in,
                              void* d_out, int out_size, void* d_ws, size_t ws_size,
                              hipStream_t stream) {
    const float* inputs = (const float*)d_in[0];  // [N, D] fp32
    const float* adj    = (const float*)d_in[1];  // [N, N] fp32
    const float* Hv     = (const float*)d_in[2];  // [D, 1] fp32
    float* out = (float*)d_out;                   // [N, D] fp32

    char* ws = (char*)d_ws;
    float*          scores = (float*)ws;                                   // 32 KB
    unsigned short* ib     = (unsigned short*)(ws + 32768);                // 4 MB
    int*            cnt    = (int*)(ws + 32768 + (size_t)NN * DD * 2);     // 32 KB
    float2*         csr    = (float2*)(ws + 65536 + (size_t)NN * DD * 2);  // 32 MB

    const size_t need = 65536 + (size_t)NN * DD * 2 + (size_t)NN * RCAP * sizeof(float2);

    if (ws_size >= need) {
        prep_kernel<true><<<NN / 4, 256, 0, stream>>>(inputs, Hv, scores, ib);
        build_kernel<<<NN / 2, 256, 0, stream>>>(adj, scores, csr, cnt);
        gather_kernel<<<NN / 2, 256, 0, stream>>>(csr, cnt, ib, adj, scores, out);
    } else {
        prep_kernel<false><<<NN / 4, 256, 0, stream>>>(inputs, Hv, scores, nullptr);
        attn_fallback<<<NN, 256, 0, stream>>>(adj, inputs, scores, out);
    }
}